// Round 7
// baseline (87.275 us; speedup 1.0000x reference)
//
#include <hip/hip_runtime.h>

// LIF: v = v*0.5 + x_t; s = (v >= 1); v -= s   (DECAY=0.5 exact in fp32 -> bit-exact vs ref)
// x: (N=16, T=64, C=256, H=16, W=16) fp32 ; v_init: (N, C, H, W) fp32
// out: spikes (N, T, C, H, W) fp32
//
// Ledger:
// R3 (kept): nt stores -> write stream doesn't evict x from L3. 115.6->85.9us.
// R4 (kept): TB=8 burst, float4/thread. 84.7us.
// R5 (reverted): float2, 2x occupancy -> 88.3us. Waves not the limiter.
// R6 (kept): nt-load v_init. 82.4us. FETCH 133MB (emergent ~50% L3 hit on x).
// R7 experiment: deterministic L3 partition of x. t<48 (192MB) = cacheable,
//   stays resident across replays; t>=48 (64MB) = nt loads, never evicts it.
//   Discriminates: Model A (total-delivery cap ~6.3TB/s -> no change) vs
//   Model B (HBM-rate bound ~4.8TB/s -> FETCH 133->70MB, dur -> ~70us).

typedef float f32x4 __attribute__((ext_vector_type(4)));

constexpr int T_STEPS = 64;
constexpr int SPATIAL = 256 * 16 * 16;   // C*H*W floats per (n,t) slice
constexpr int SPAT4   = SPATIAL / 4;     // 16384 float4 per slice
constexpr int N_BATCH = 16;
constexpr int TB      = 8;               // t-steps per load/store burst
constexpr int NT      = T_STEPS / TB;    // 8 bursts
constexpr int TCACHE  = 48;              // t < TCACHE: L3-allocating loads (192 MB resident)

__global__ __launch_bounds__(256, 8)
void lif_kernel(const f32x4* __restrict__ x,
                const f32x4* __restrict__ v_init,
                f32x4* __restrict__ out)
{
    const int gid = blockIdx.x * blockDim.x + threadIdx.x;  // float4 idx over (N, SPAT4)
    const int n   = gid >> 14;             // / 16384
    const int s4  = gid & (SPAT4 - 1);

    const int nbase = n * (T_STEPS * SPAT4);   // float4 units; max 16.7M fits int32
    const f32x4* __restrict__ xp = x   + nbase + s4;
    f32x4*       __restrict__ op = out + nbase + s4;

    // nt-load: v_init streamed once; keep it out of L3
    f32x4 v = __builtin_nontemporal_load(&v_init[n * SPAT4 + s4]);

    #pragma unroll
    for (int tb = 0; tb < NT; ++tb) {
        f32x4 b[TB];
        // burst-load TB slices; t<TCACHE allocate in L3 (resident set),
        // t>=TCACHE nontemporal (never evict the resident set)
        #pragma unroll
        for (int k = 0; k < TB; ++k) {
            const int t = tb * TB + k;          // compile-time after unroll
            if (t < TCACHE)
                b[k] = xp[t * SPAT4];
            else
                b[k] = __builtin_nontemporal_load(&xp[t * SPAT4]);
        }

        // serial v-recurrence; overwrite b[k] with the spike (no extra regs)
        #pragma unroll
        for (int k = 0; k < TB; ++k) {
            f32x4 s;
            v.x = v.x * 0.5f + b[k].x;  s.x = (v.x >= 1.0f) ? 1.0f : 0.0f;  v.x -= s.x;
            v.y = v.y * 0.5f + b[k].y;  s.y = (v.y >= 1.0f) ? 1.0f : 0.0f;  v.y -= s.y;
            v.z = v.z * 0.5f + b[k].z;  s.z = (v.z >= 1.0f) ? 1.0f : 0.0f;  v.z -= s.z;
            v.w = v.w * 0.5f + b[k].w;  s.w = (v.w >= 1.0f) ? 1.0f : 0.0f;  v.w -= s.w;
            b[k] = s;
        }

        // burst-store TB slices, nontemporal (don't allocate in L2/L3)
        #pragma unroll
        for (int k = 0; k < TB; ++k)
            __builtin_nontemporal_store(b[k], &op[(tb * TB + k) * SPAT4]);
    }
}

extern "C" void kernel_launch(void* const* d_in, const int* in_sizes, int n_in,
                              void* d_out, int out_size, void* d_ws, size_t ws_size,
                              hipStream_t stream)
{
    const f32x4* x      = (const f32x4*)d_in[0];
    const f32x4* v_init = (const f32x4*)d_in[1];
    f32x4*       out    = (f32x4*)d_out;

    const int total4 = N_BATCH * SPAT4;     // 262144 threads
    const int block  = 256;
    const int grid   = total4 / block;      // 1024 blocks

    lif_kernel<<<grid, block, 0, stream>>>(x, v_init, out);
}

// Round 8
// 83.121 us; speedup vs baseline: 1.0500x; 1.0500x over previous
//
#include <hip/hip_runtime.h>

// LIF: v = v*0.5 + x_t; s = (v >= 1); v -= s   (DECAY=0.5 exact in fp32 -> bit-exact vs ref)
// x: (N=16, T=64, C=256, H=16, W=16) fp32 ; v_init: (N, C, H, W) fp32
// out: spikes (N, T, C, H, W) fp32
//
// Ledger:
// R3 (kept): nt STORES -> write stream doesn't evict x from L3 across graph
//   replays. FETCH 260->133 MB, 115.6->85.9 us.
// R4 (kept): TB=8 burst, float4/thread. 84.7 us.
// R5 (reverted): float2, 2x occupancy (53%) -> 88.3 us. Waves not the limiter.
// R6 (kept, BEST): nt-load v_init. 82.4 us. 6.26 TB/s aggregate = 99.5% of
//   the 6.29 TB/s copy ceiling; HBM 4.79 TB/s.
// R7 (reverted): deterministic L3 partition via nt-LOADS on x -> FETCH
//   byte-identical (hint doesn't steer MALL), dur +5 us. nt-load path slower.
// R8: revert to R6 exactly. At roofline: bytes minimal, hints exhausted,
//   parallelism levers all neutral/negative.

typedef float f32x4 __attribute__((ext_vector_type(4)));

constexpr int T_STEPS = 64;
constexpr int SPATIAL = 256 * 16 * 16;   // C*H*W floats per (n,t) slice
constexpr int SPAT4   = SPATIAL / 4;     // 16384 float4 per slice
constexpr int N_BATCH = 16;
constexpr int TB      = 8;               // t-steps per load/store burst
constexpr int NT      = T_STEPS / TB;    // 8 bursts

__global__ __launch_bounds__(256, 8)
void lif_kernel(const f32x4* __restrict__ x,
                const f32x4* __restrict__ v_init,
                f32x4* __restrict__ out)
{
    const int gid = blockIdx.x * blockDim.x + threadIdx.x;  // float4 idx over (N, SPAT4)
    const int n   = gid >> 14;             // / 16384
    const int s4  = gid & (SPAT4 - 1);

    const int nbase = n * (T_STEPS * SPAT4);   // float4 units; max 16.7M fits int32
    const f32x4* __restrict__ xp = x   + nbase + s4;
    f32x4*       __restrict__ op = out + nbase + s4;

    // nt-load: v_init streamed once; keep it out of L3 so x gets the space
    f32x4 v = __builtin_nontemporal_load(&v_init[n * SPAT4 + s4]);

    #pragma unroll
    for (int tb = 0; tb < NT; ++tb) {
        f32x4 b[TB];
        // burst-load TB slices (independent addresses -> deep vmcnt pipeline)
        #pragma unroll
        for (int k = 0; k < TB; ++k)
            b[k] = xp[(tb * TB + k) * SPAT4];

        // serial v-recurrence; overwrite b[k] with the spike (no extra regs)
        #pragma unroll
        for (int k = 0; k < TB; ++k) {
            f32x4 s;
            v.x = v.x * 0.5f + b[k].x;  s.x = (v.x >= 1.0f) ? 1.0f : 0.0f;  v.x -= s.x;
            v.y = v.y * 0.5f + b[k].y;  s.y = (v.y >= 1.0f) ? 1.0f : 0.0f;  v.y -= s.y;
            v.z = v.z * 0.5f + b[k].z;  s.z = (v.z >= 1.0f) ? 1.0f : 0.0f;  v.z -= s.z;
            v.w = v.w * 0.5f + b[k].w;  s.w = (v.w >= 1.0f) ? 1.0f : 0.0f;  v.w -= s.w;
            b[k] = s;
        }

        // burst-store TB slices, nontemporal (don't allocate in L2/L3)
        #pragma unroll
        for (int k = 0; k < TB; ++k)
            __builtin_nontemporal_store(b[k], &op[(tb * TB + k) * SPAT4]);
    }
}

extern "C" void kernel_launch(void* const* d_in, const int* in_sizes, int n_in,
                              void* d_out, int out_size, void* d_ws, size_t ws_size,
                              hipStream_t stream)
{
    const f32x4* x      = (const f32x4*)d_in[0];
    const f32x4* v_init = (const f32x4*)d_in[1];
    f32x4*       out    = (f32x4*)d_out;

    const int total4 = N_BATCH * SPAT4;     // 262144 threads
    const int block  = 256;
    const int grid   = total4 / block;      // 1024 blocks

    lif_kernel<<<grid, block, 0, stream>>>(x, v_init, out);
}